// Round 3
// baseline (8184.670 us; speedup 1.0000x reference)
//
#include <hip/hip_runtime.h>

#define TT 1000
#define FF 20
#define HH 256
#define OO 200
#define ZR 256           // zero-row index in padded tables (stride 256 floats, 257 rows)

typedef unsigned int uint;

__device__ __forceinline__ int rfl(int v) { return __builtin_amdgcn_readfirstlane(v); }

// Uniform-mask row gather over a padded table (257 rows x 256 float cols).
// Rows = rowbase + set bits of m; empty pipeline slots read the all-zero row 256,
// so there are NO per-element guards. All mask/row math is wave-uniform (scalar pipe);
// loads are SGPR-base + fixed VGPR byte offset. 16 loads in flight per chunk.
__device__ __forceinline__ float4 gatherZ(const float* __restrict__ tab,
                                          uint m, int rowbase, int cx) {
    float4 acc = make_float4(0.f, 0.f, 0.f, 0.f);
    while (m) {
        const float* p[16];
#pragma unroll
        for (int u = 0; u < 16; ++u) {
            int bb = __ffs((int)m);
            int row = rfl(bb ? (rowbase + bb - 1) : ZR);
            p[u] = tab + ((size_t)row << 8);
            m &= (m - 1u);
        }
        float4 v[16];
#pragma unroll
        for (int u = 0; u < 16; ++u)
            v[u] = *(const float4*)(p[u] + cx);
#pragma unroll
        for (int u = 0; u < 16; ++u) {
            acc.x += v[u].x; acc.y += v[u].y; acc.z += v[u].z; acc.w += v[u].w;
        }
    }
    return acc;
}

__global__ __launch_bounds__(1024, 1) void snn_main(
    const float* __restrict__ x,
    const float* __restrict__ W1, const float* __restrict__ b1,
    const float* __restrict__ beta1,
    const float* __restrict__ b2, const float* __restrict__ beta2,
    const float* __restrict__ V1z, const float* __restrict__ V2z,
    const float* __restrict__ W2Tz, const float* __restrict__ WTz,
    const float* __restrict__ alpha_out, const float* __restrict__ beta_out,
    float* __restrict__ out)
{
    __shared__ float w1t_s[FF * HH];   // W1 transposed [f][h]
    __shared__ float wx_s[2][HH];      // b1 + W1 x_t, double-buffered by t parity
    __shared__ float xts[2][FF];       // x[t] double buffer
    __shared__ float pV1[8 * HH];      // Vrec1 partials (8 row-eighths)
    __shared__ float pV2[8 * HH];
    __shared__ float pW2[8 * HH];
    __shared__ float pO[8 * HH];       // Wout partials (cols 0..199 used)
    __shared__ uint m1s[8], m2s[8];    // 256-bit spike masks as 8x32

    const int tid = threadIdx.x;
    const int b   = blockIdx.x;
    const float* xg = x + (size_t)b * TT * FF;

    // ---- init ----
    for (int idx = tid; idx < FF * HH; idx += 1024) {
        int h = idx / FF, f = idx - h * FF;
        w1t_s[f * HH + h] = W1[idx];
    }
    if (tid < FF) { xts[0][tid] = xg[tid]; xts[1][tid] = xg[FF + tid]; }
    if (tid < 8) { m1s[tid] = 0u; m2s[tid] = 0u; }
    for (int idx = tid; idx < 8 * HH; idx += 1024) { pV1[idx] = 0.f; pV2[idx] = 0.f; }

    float syn1 = 0.f, mem1 = 0.f, syn2 = 0.f, mem2 = 0.f;
    float b2r = 0.f, beta1r = 0.f, beta2r = 0.f;
    bool spk1 = false, spk2 = false;
    if (tid < HH) {
        beta1r = beta1[tid]; beta2r = beta2[tid]; b2r = b2[tid];
    }
    float b1r2 = 0.f;
    if (tid >= HH && tid < 2 * HH) b1r2 = b1[tid - HH];

    float synO[4] = {0,0,0,0}, memO[4] = {0,0,0,0}, accO[4] = {0,0,0,0};
    float aOr[4] = {0,0,0,0}, bOr[4] = {0,0,0,0};
    bool  spkO[4] = {false,false,false,false};
    if (tid >= 960) {
        int o0 = tid - 960;
#pragma unroll
        for (int r = 0; r < 4; ++r) {
            int o = o0 + (r << 6);
            if (o < OO) { aOr[r] = alpha_out[o]; bOr[r] = beta_out[o]; }
        }
    }
    __syncthreads();
    if (tid < HH) {   // wx for t=0
        float wx = b1[tid];
#pragma unroll
        for (int f = 0; f < FF; ++f) wx = fmaf(xts[0][f], w1t_s[f * HH + tid], wx);
        wx_s[0][tid] = wx;
    }
    __syncthreads();

    for (int t = 0; t < TT; ++t) {
        // ---- B: layer-1 update (threads 0..255) ----
        if (tid < HH) {
            float g1 = pV1[tid] + pV1[HH + tid] + pV1[2*HH + tid] + pV1[3*HH + tid]
                     + pV1[4*HH + tid] + pV1[5*HH + tid] + pV1[6*HH + tid] + pV1[7*HH + tid];
            syn1 = fmaf(0.95f, syn1, wx_s[t & 1][tid] + g1);
            mem1 = fmaf(beta1r, mem1, syn1) - (spk1 ? 1.f : 0.f);
            spk1 = mem1 > 1.0f;
            unsigned long long bal = __ballot(spk1 ? 1 : 0);
            if ((tid & 63) == 0) {
                int w = tid >> 6;
                m1s[2*w]   = (uint)bal;
                m1s[2*w+1] = (uint)(bal >> 32);
            }
        }
        __syncthreads();
        // ---- C: gather W2T(m1[t]) and Vrec2(m2[t-1]) ----
        if (tid < 512) {
            int e = tid >> 6, cq = tid & 63;
            uint m = (uint)rfl((int)m1s[e]);
            float4 s = gatherZ(W2Tz, m, e << 5, cq << 2);
            *(float4*)&pW2[(e << 8) + (cq << 2)] = s;
        } else {
            int tt2 = tid - 512;
            int e = tt2 >> 6, cq = tt2 & 63;
            uint m = (uint)rfl((int)m2s[e]);
            float4 s = gatherZ(V2z, m, e << 5, cq << 2);
            *(float4*)&pV2[(e << 8) + (cq << 2)] = s;
        }
        __syncthreads();
        // ---- D: layer-2 update (0..255) + wx(t+1) (256..511) ----
        if (tid < HH) {
            float gA = pW2[tid] + pW2[HH + tid] + pW2[2*HH + tid] + pW2[3*HH + tid]
                     + pW2[4*HH + tid] + pW2[5*HH + tid] + pW2[6*HH + tid] + pW2[7*HH + tid];
            float gB = pV2[tid] + pV2[HH + tid] + pV2[2*HH + tid] + pV2[3*HH + tid]
                     + pV2[4*HH + tid] + pV2[5*HH + tid] + pV2[6*HH + tid] + pV2[7*HH + tid];
            syn2 = fmaf(0.95f, syn2, b2r + gA + gB);
            mem2 = fmaf(beta2r, mem2, syn2) - (spk2 ? 1.f : 0.f);
            spk2 = mem2 > 1.0f;
            unsigned long long bal = __ballot(spk2 ? 1 : 0);
            if ((tid & 63) == 0) {
                int w = tid >> 6;
                m2s[2*w]   = (uint)bal;
                m2s[2*w+1] = (uint)(bal >> 32);
            }
        } else if (tid < 2 * HH && (t + 1) < TT) {
            int j2 = tid - HH;
            const float* xx = xts[(t + 1) & 1];
            float wx = b1r2;
#pragma unroll
            for (int f = 0; f < FF; ++f) wx = fmaf(xx[f], w1t_s[f * HH + j2], wx);
            wx_s[(t + 1) & 1][j2] = wx;
        }
        __syncthreads();
        // ---- E: gather Wout(m2[t]) -> pO, Vrec1(m1[t]) -> pV1, prefetch x[t+2] ----
        if (tid < 512) {
            int e = tid >> 6, cq = tid & 63;
            if (cq < 50) {
                uint m = (uint)rfl((int)m2s[e]);
                float4 s = gatherZ(WTz, m, e << 5, cq << 2);
                *(float4*)&pO[(e << 8) + (cq << 2)] = s;
            } else {
                int id = e * 14 + (cq - 50);
                if (id < FF && (t + 2) < TT) xts[t & 1][id] = xg[(size_t)(t + 2) * FF + id];
            }
        } else {
            int tt2 = tid - 512;
            int e = tt2 >> 6, cq = tt2 & 63;
            uint m = (uint)rfl((int)m1s[e]);
            float4 s = gatherZ(V1z, m, e << 5, cq << 2);
            *(float4*)&pV1[(e << 8) + (cq << 2)] = s;
        }
        __syncthreads();
        // ---- F: output layer (last wave; overlaps B(t+1)) ----
        if (tid >= 960) {
            int o0 = tid - 960;
            float mmax = -3.402823466e38f;
#pragma unroll
            for (int r = 0; r < 4; ++r) {
                int o = o0 + (r << 6);
                if (o < OO) {
                    float ot = pO[o] + pO[HH + o] + pO[2*HH + o] + pO[3*HH + o]
                             + pO[4*HH + o] + pO[5*HH + o] + pO[6*HH + o] + pO[7*HH + o];
                    synO[r] = fmaf(aOr[r], synO[r], ot);
                    memO[r] = fmaf(bOr[r], memO[r], synO[r]) - (spkO[r] ? 1.f : 0.f);
                    spkO[r] = memO[r] > 1.0f;
                    mmax = fmaxf(mmax, memO[r]);
                }
            }
#pragma unroll
            for (int off = 32; off; off >>= 1) mmax = fmaxf(mmax, __shfl_xor(mmax, off, 64));
            float ex[4]; float se = 0.f;
#pragma unroll
            for (int r = 0; r < 4; ++r) {
                int o = o0 + (r << 6);
                ex[r] = (o < OO) ? expf(memO[r] - mmax) : 0.f;
                se += ex[r];
            }
#pragma unroll
            for (int off = 32; off; off >>= 1) se += __shfl_xor(se, off, 64);
            if (t > 10) {
#pragma unroll
                for (int r = 0; r < 4; ++r) accO[r] += ex[r] / se;
            }
        }
        // no barrier: B(t+1) deps (pV1 from E(t), wx from D(t)) sit behind the E barrier
    }

    if (tid >= 960) {
        int o0 = tid - 960;
#pragma unroll
        for (int r = 0; r < 4; ++r) {
            int o = o0 + (r << 6);
            if (o < OO) out[(size_t)b * OO + o] = accO[r];
        }
    }
}

// one-shot prep: padded 257x256 tables, zero diagonal (V1z/V2z), zero row 256.
//  V1z[r][c]  = (r<256 && r!=c) ? Vrec1[r][c] : 0
//  V2z[r][c]  = (r<256 && r!=c) ? Vrec2[r][c] : 0
//  W2Tz[h][g] = (h<256) ? W2[g][h] : 0
//  WTz[h][o]  = (h<256 && o<200) ? Wout[o][h] : 0
__global__ void prep_kernel(const float* __restrict__ Vrec1, const float* __restrict__ Vrec2,
                            const float* __restrict__ W2, const float* __restrict__ Wout,
                            float* __restrict__ V1z, float* __restrict__ V2z,
                            float* __restrict__ W2Tz, float* __restrict__ WTz) {
    int idx = blockIdx.x * blockDim.x + threadIdx.x;   // 257*256 entries
    if (idx >= 257 * 256) return;
    int r = idx >> 8, c = idx & 255;
    float v1 = 0.f, v2 = 0.f, w2 = 0.f, wo = 0.f;
    if (r < 256) {
        if (r != c) { v1 = Vrec1[r * HH + c]; v2 = Vrec2[r * HH + c]; }
        w2 = W2[c * HH + r];
        if (c < OO) wo = Wout[c * HH + r];
    }
    V1z[idx] = v1; V2z[idx] = v2; W2Tz[idx] = w2; WTz[idx] = wo;
}

extern "C" void kernel_launch(void* const* d_in, const int* in_sizes, int n_in,
                              void* d_out, int out_size, void* d_ws, size_t ws_size,
                              hipStream_t stream) {
    const float* x       = (const float*)d_in[0];
    const float* W1      = (const float*)d_in[1];
    const float* b1      = (const float*)d_in[2];
    const float* Vrec1   = (const float*)d_in[3];
    const float* beta1   = (const float*)d_in[4];
    const float* W2      = (const float*)d_in[5];
    const float* b2      = (const float*)d_in[6];
    const float* Vrec2   = (const float*)d_in[7];
    const float* beta2   = (const float*)d_in[8];
    const float* Wout    = (const float*)d_in[9];
    const float* alpha_o = (const float*)d_in[10];
    const float* beta_o  = (const float*)d_in[11];

    const int TBL = 257 * 256;       // floats per padded table
    float* V1z  = (float*)d_ws;
    float* V2z  = V1z + TBL;
    float* W2Tz = V2z + TBL;
    float* WTz  = W2Tz + TBL;        // total ~1.05 MB of ws

    prep_kernel<<<(TBL + 255) / 256, 256, 0, stream>>>(Vrec1, Vrec2, W2, Wout,
                                                       V1z, V2z, W2Tz, WTz);
    snn_main<<<128, 1024, 0, stream>>>(x, W1, b1, beta1, b2, beta2,
                                       V1z, V2z, W2Tz, WTz,
                                       alpha_o, beta_o, (float*)d_out);
}

// Round 6
// 2867.180 us; speedup vs baseline: 2.8546x; 2.8546x over previous
//
#include <hip/hip_runtime.h>

#define TT 1000
#define FF 20
#define HH 256
#define OO 200
#define ZR 256           // zero-row index in padded int32 tables (257 rows x 256 cols)

typedef unsigned int uint;
typedef unsigned long long ull;

__device__ __forceinline__ int rfl(int v) { return __builtin_amdgcn_readfirstlane(v); }

// Signed int toggle-gather batch: N rows from toggle mask m (wave-uniform), sign from
// current mask cur (+ if now active, - if now inactive). Empty slots hit zero row ZR.
// Mask/row/sign math is wave-uniform (scalar pipe); N 16B loads in flight before use.
// Accumulation is EXACT int64: (v ^ sm) - sm negates when sm=-1.
template<int N>
__device__ __forceinline__ void gstepI(const int* __restrict__ tab, uint& m, uint cur,
                                       int rowbase, int cx, long long* acc) {
    const int* p[N];
    int sm[N];
#pragma unroll
    for (int u = 0; u < N; ++u) {
        int bb = __ffs((int)m);
        int k  = (bb ? bb : 1) - 1;
        int row = rfl(bb ? (rowbase + k) : ZR);
        int pos = rfl(bb ? (int)((cur >> k) & 1u) : 1);
        sm[u] = pos ? 0 : -1;
        p[u]  = tab + ((size_t)row << 8);
        m &= (m - 1u);
    }
    int4 v[N];
#pragma unroll
    for (int u = 0; u < N; ++u) v[u] = *(const int4*)(p[u] + cx);
#pragma unroll
    for (int u = 0; u < N; ++u) {
        acc[0] += (long long)((v[u].x ^ sm[u]) - sm[u]);
        acc[1] += (long long)((v[u].y ^ sm[u]) - sm[u]);
        acc[2] += (long long)((v[u].z ^ sm[u]) - sm[u]);
        acc[3] += (long long)((v[u].w ^ sm[u]) - sm[u]);
    }
}

// Adaptive-depth signed toggle gather; zero-row waste <= 3 per mask word.
// Result committed to persistent LDS int64 drive via ds_add_u64 (exact, order-free).
__device__ __forceinline__ void gatherI(const int* __restrict__ tab, uint m, uint cur,
                                        int rowbase, int cx, long long* dst) {
    long long acc[4] = {0, 0, 0, 0};
    while (m) {
        int pc = rfl(__popc(m));
        if (pc > 12)      gstepI<16>(tab, m, cur, rowbase, cx, acc);
        else if (pc > 8)  gstepI<12>(tab, m, cur, rowbase, cx, acc);
        else if (pc > 4)  gstepI<8>(tab, m, cur, rowbase, cx, acc);
        else              gstepI<4>(tab, m, cur, rowbase, cx, acc);
    }
#pragma unroll
    for (int c = 0; c < 4; ++c)
        atomicAdd((ull*)&dst[cx + c], (ull)acc[c]);
}

#define INV30 9.31322574615478515625e-10   // 2^-30, exact

__global__ __launch_bounds__(1024, 1) void snn_main(
    const float* __restrict__ x,
    const float* __restrict__ W1, const float* __restrict__ b1,
    const float* __restrict__ beta1,
    const float* __restrict__ b2, const float* __restrict__ beta2,
    const int* __restrict__ V1q, const int* __restrict__ V2q,
    const int* __restrict__ W2Tq, const int* __restrict__ WTq,
    const float* __restrict__ alpha_out, const float* __restrict__ beta_out,
    float* __restrict__ out)
{
    __shared__ float w1t_s[FF * HH];     // W1 transposed [f][h] (fp32, exact drive)
    __shared__ float wx_s[2][HH];        // b1 + W1 x_t, double-buffered by t parity
    __shared__ float xts[2][FF];         // x[t] double buffer
    __shared__ long long pV1q[HH];       // persistent int64 drives (scale 2^-30)
    __shared__ long long pV2q[HH];
    __shared__ long long pW2q[HH];
    __shared__ long long pOq[HH];
    __shared__ uint m1s[8], m2s[8];      // current 256-bit spike masks (8x32)
    __shared__ uint t1s[8], t2s[8];      // toggle masks this step

    const int tid = threadIdx.x;
    const int b   = blockIdx.x;
    const float* xg = x + (size_t)b * TT * FF;

    // ---- init ----
    for (int idx = tid; idx < FF * HH; idx += 1024) {
        int h = idx / FF, f = idx - h * FF;
        w1t_s[f * HH + h] = W1[idx];
    }
    if (tid < FF) { xts[0][tid] = xg[tid]; xts[1][tid] = xg[FF + tid]; }
    if (tid < 8) { m1s[tid] = 0u; m2s[tid] = 0u; t1s[tid] = 0u; t2s[tid] = 0u; }
    if (tid < HH) { pV1q[tid] = 0; pV2q[tid] = 0; pW2q[tid] = 0; pOq[tid] = 0; }

    float syn1 = 0.f, mem1 = 0.f, syn2 = 0.f, mem2 = 0.f;
    float b2r = 0.f, beta1r = 0.f, beta2r = 0.f;
    bool spk1 = false, spk2 = false;
    if (tid < HH) {
        beta1r = beta1[tid]; beta2r = beta2[tid]; b2r = b2[tid];
    }
    float b1r2 = 0.f;
    if (tid >= HH && tid < 2 * HH) b1r2 = b1[tid - HH];

    float synO[4] = {0,0,0,0}, memO[4] = {0,0,0,0}, accO[4] = {0,0,0,0};
    float aOr[4] = {0,0,0,0}, bOr[4] = {0,0,0,0};
    bool  spkO[4] = {false,false,false,false};
    if (tid >= 960) {
        int o0 = tid - 960;
#pragma unroll
        for (int r = 0; r < 4; ++r) {
            int o = o0 + (r << 6);
            if (o < OO) { aOr[r] = alpha_out[o]; bOr[r] = beta_out[o]; }
        }
    }
    __syncthreads();
    if (tid < HH) {   // wx for t=0
        float wx = b1[tid];
#pragma unroll
        for (int f = 0; f < FF; ++f) wx = fmaf(xts[0][f], w1t_s[f * HH + tid], wx);
        wx_s[0][tid] = wx;
    }
    __syncthreads();

    for (int t = 0; t < TT; ++t) {
        // ---- B: layer-1 update (threads 0..255); emit m1 + toggle t1 ----
        if (tid < HH) {
            float g1 = (float)((double)pV1q[tid] * INV30);
            syn1 = fmaf(0.95f, syn1, wx_s[t & 1][tid] + g1);
            mem1 = fmaf(beta1r, mem1, syn1) - (spk1 ? 1.f : 0.f);
            spk1 = mem1 > 1.0f;
            unsigned long long bal = __ballot(spk1 ? 1 : 0);
            if ((tid & 63) == 0) {
                int w = tid >> 6;
                uint n0 = (uint)bal, n1 = (uint)(bal >> 32);
                t1s[2*w]   = m1s[2*w]   ^ n0;
                t1s[2*w+1] = m1s[2*w+1] ^ n1;
                m1s[2*w]   = n0;
                m1s[2*w+1] = n1;
            }
        }
        __syncthreads();
        // ---- C: toggle-gathers on m1: pW2q (waves 0-7), pV1q (waves 8-15) ----
        if (tid < 512) {
            int e = tid >> 6, cq = tid & 63;
            uint tm = (uint)rfl((int)t1s[e]);
            if (tm) {
                uint cm = (uint)rfl((int)m1s[e]);
                gatherI(W2Tq, tm, cm, e << 5, cq << 2, pW2q);
            }
        } else {
            int tt2 = tid - 512;
            int e = tt2 >> 6, cq = tt2 & 63;
            uint tm = (uint)rfl((int)t1s[e]);
            if (tm) {
                uint cm = (uint)rfl((int)m1s[e]);
                gatherI(V1q, tm, cm, e << 5, cq << 2, pV1q);
            }
        }
        __syncthreads();
        // ---- D: layer-2 update (0..255) + wx(t+1) (256..511) + x prefetch (512..531) ----
        if (tid < HH) {
            float gA = (float)((double)pW2q[tid] * INV30);
            float gB = (float)((double)pV2q[tid] * INV30);
            syn2 = fmaf(0.95f, syn2, b2r + gA + gB);
            mem2 = fmaf(beta2r, mem2, syn2) - (spk2 ? 1.f : 0.f);
            spk2 = mem2 > 1.0f;
            unsigned long long bal = __ballot(spk2 ? 1 : 0);
            if ((tid & 63) == 0) {
                int w = tid >> 6;
                uint n0 = (uint)bal, n1 = (uint)(bal >> 32);
                t2s[2*w]   = m2s[2*w]   ^ n0;
                t2s[2*w+1] = m2s[2*w+1] ^ n1;
                m2s[2*w]   = n0;
                m2s[2*w+1] = n1;
            }
        } else if (tid < 2 * HH) {
            if ((t + 1) < TT) {
                int j2 = tid - HH;
                const float* xx = xts[(t + 1) & 1];
                float wx = b1r2;
#pragma unroll
                for (int f = 0; f < FF; ++f) wx = fmaf(xx[f], w1t_s[f * HH + j2], wx);
                wx_s[(t + 1) & 1][j2] = wx;
            }
        } else if (tid < 512 + FF) {
            int id = tid - 512;
            if ((t + 2) < TT) xts[t & 1][id] = xg[(size_t)(t + 2) * FF + id];
        }
        __syncthreads();
        // ---- E: toggle-gathers on m2: pOq (waves 0-7), pV2q (waves 8-15) ----
        if (tid < 512) {
            int e = tid >> 6, cq = tid & 63;
            uint tm = (uint)rfl((int)t2s[e]);
            if (tm) {
                uint cm = (uint)rfl((int)m2s[e]);
                gatherI(WTq, tm, cm, e << 5, cq << 2, pOq);
            }
        } else {
            int tt2 = tid - 512;
            int e = tt2 >> 6, cq = tt2 & 63;
            uint tm = (uint)rfl((int)t2s[e]);
            if (tm) {
                uint cm = (uint)rfl((int)m2s[e]);
                gatherI(V2q, tm, cm, e << 5, cq << 2, pV2q);
            }
        }
        __syncthreads();
        // ---- F: output layer (last wave; overlaps B(t+1) on waves 0..3) ----
        if (tid >= 960) {
            int o0 = tid - 960;
            float mmax = -3.402823466e38f;
#pragma unroll
            for (int r = 0; r < 4; ++r) {
                int o = o0 + (r << 6);
                if (o < OO) {
                    float ot = (float)((double)pOq[o] * INV30);
                    synO[r] = fmaf(aOr[r], synO[r], ot);
                    memO[r] = fmaf(bOr[r], memO[r], synO[r]) - (spkO[r] ? 1.f : 0.f);
                    spkO[r] = memO[r] > 1.0f;
                    mmax = fmaxf(mmax, memO[r]);
                }
            }
#pragma unroll
            for (int off = 32; off; off >>= 1) mmax = fmaxf(mmax, __shfl_xor(mmax, off, 64));
            float ex[4]; float se = 0.f;
#pragma unroll
            for (int r = 0; r < 4; ++r) {
                int o = o0 + (r << 6);
                ex[r] = (o < OO) ? expf(memO[r] - mmax) : 0.f;
                se += ex[r];
            }
#pragma unroll
            for (int off = 32; off; off >>= 1) se += __shfl_xor(se, off, 64);
            if (t > 10) {
#pragma unroll
                for (int r = 0; r < 4; ++r) accO[r] += ex[r] / se;
            }
        }
        // no barrier: E(t+1) (next writer of pOq) is >=3 barriers away; wave 15
        // joins B(t+1)'s barrier after F completes.
    }

    if (tid >= 960) {
        int o0 = tid - 960;
#pragma unroll
        for (int r = 0; r < 4; ++r) {
            int o = o0 + (r << 6);
            if (o < OO) out[(size_t)b * OO + o] = accO[r];
        }
    }
}

// one-shot prep: padded 257x256 int32 fixed-point (2^30) tables, zero diagonal
// (V1q/V2q), zero row 256, WTq cols >= 200 zero.
__global__ void prep_kernel(const float* __restrict__ Vrec1, const float* __restrict__ Vrec2,
                            const float* __restrict__ W2, const float* __restrict__ Wout,
                            int* __restrict__ V1q, int* __restrict__ V2q,
                            int* __restrict__ W2Tq, int* __restrict__ WTq) {
    int idx = blockIdx.x * blockDim.x + threadIdx.x;   // 257*256 entries
    if (idx >= 257 * 256) return;
    int r = idx >> 8, c = idx & 255;
    float v1 = 0.f, v2 = 0.f, w2 = 0.f, wo = 0.f;
    if (r < 256) {
        if (r != c) { v1 = Vrec1[r * HH + c]; v2 = Vrec2[r * HH + c]; }
        w2 = W2[c * HH + r];
        if (c < OO) wo = Wout[c * HH + r];
    }
    const float S = 1073741824.0f;   // 2^30
    V1q[idx]  = __float2int_rn(v1 * S);
    V2q[idx]  = __float2int_rn(v2 * S);
    W2Tq[idx] = __float2int_rn(w2 * S);
    WTq[idx]  = __float2int_rn(wo * S);
}

extern "C" void kernel_launch(void* const* d_in, const int* in_sizes, int n_in,
                              void* d_out, int out_size, void* d_ws, size_t ws_size,
                              hipStream_t stream) {
    const float* x       = (const float*)d_in[0];
    const float* W1      = (const float*)d_in[1];
    const float* b1      = (const float*)d_in[2];
    const float* Vrec1   = (const float*)d_in[3];
    const float* beta1   = (const float*)d_in[4];
    const float* W2      = (const float*)d_in[5];
    const float* b2      = (const float*)d_in[6];
    const float* Vrec2   = (const float*)d_in[7];
    const float* beta2   = (const float*)d_in[8];
    const float* Wout    = (const float*)d_in[9];
    const float* alpha_o = (const float*)d_in[10];
    const float* beta_o  = (const float*)d_in[11];

    const int TBL = 257 * 256;       // int32 per padded table
    int* V1q  = (int*)d_ws;
    int* V2q  = V1q + TBL;
    int* W2Tq = V2q + TBL;
    int* WTq  = W2Tq + TBL;          // total ~1.05 MB of ws

    prep_kernel<<<(TBL + 255) / 256, 256, 0, stream>>>(Vrec1, Vrec2, W2, Wout,
                                                       V1q, V2q, W2Tq, WTq);
    snn_main<<<128, 1024, 0, stream>>>(x, W1, b1, beta1, b2, beta2,
                                       V1q, V2q, W2Tq, WTq,
                                       alpha_o, beta_o, (float*)d_out);
}